// Round 11
// baseline (246.651 us; speedup 1.0000x reference)
//
#include <hip/hip_runtime.h>
#include <math.h>

#define B_ 8
#define N_ 2048
#define K_ 8
#define IN_ 5
#define BN_ (B_*N_)
#define NEDGE_ (BN_*K_)
#define GRP 8
#define SEG_ 32
#define CSEG_ (N_/SEG_)   // 64 candidates per segment
#define CHUNKS_ (N_/GRP)  // 256 combine-blocks per batch

typedef unsigned short ushort8_ __attribute__((ext_vector_type(8)));
typedef short bf16x8_ __attribute__((ext_vector_type(8)));
typedef float f32x4_ __attribute__((ext_vector_type(4)));

__device__ inline unsigned short f2bf(float f) {
    unsigned int u = __float_as_uint(f);
    u += 0x7fffu + ((u >> 16) & 1u);
    return (unsigned short)(u >> 16);
}
__device__ inline float bf2f(unsigned short h) {
    return __uint_as_float(((unsigned int)h) << 16);
}

// ---------------- kNN phase 1: per-segment top-8; raw-bit keys (d>=0 for this data), scalar loads ----------------
__global__ __launch_bounds__(256) void knn_part(const float4* __restrict__ P4,
                                                unsigned long long* __restrict__ part) {
    int tid = threadIdx.x;
    int bblk = blockIdx.x >> 3;         // batch id: provably uniform (8 blocks per batch)
    int q = blockIdx.x * 256 + tid;
    int nloc = q & (N_-1);
    int seg = blockIdx.y;

    float4 qp = P4[q];
    float qx2 = -2.0f*qp.x, qy2 = -2.0f*qp.y, qz2 = -2.0f*qp.z;
    float qsq = qp.w;

    unsigned int bd[K_], bi[K_];
#pragma unroll
    for (int k = 0; k < K_; ++k) { bd[k] = 0xFFFFFFFFu; bi[k] = 0xFFFFFFFFu; }

    const float4* __restrict__ cb = P4 + ((size_t)bblk << 11) + (size_t)seg*CSEG_;  // uniform -> s_load
    int jbase = seg * CSEG_;

#pragma unroll 8
    for (int jj = 0; jj < CSEG_; ++jj) {
        float4 c = cb[jj];
        float d = qsq + c.w;
        d = fmaf(qx2, c.x, d);
        d = fmaf(qy2, c.y, d);
        d = fmaf(qz2, c.z, d);
        // raw float bits are monotone for d>=0 (min pairwise d^2 ~3e-4 >> 1e-6 fp error margin)
        unsigned int cd = __float_as_uint(d);
        int jg = jbase + jj;
        cd = (jg == nloc) ? 0xFFFFFFFFu : cd;   // self-exclusion -> max key, always expelled
        unsigned int ci = (unsigned int)jg;
        // stable unconditional insert: strict < keeps equal-d entries in idx (scan) order
#pragma unroll
        for (int p = 0; p < K_; ++p) {
            bool lt = cd < bd[p];
            unsigned int nd = lt ? cd : bd[p];
            unsigned int xd = lt ? bd[p] : cd;
            unsigned int ni = lt ? ci : bi[p];
            unsigned int xi = lt ? bi[p] : ci;
            bd[p] = nd; cd = xd; bi[p] = ni; ci = xi;
        }
    }
    unsigned long long* op = part + ((size_t)seg * BN_ + q) * K_;
#pragma unroll
    for (int k = 0; k < K_; ++k)
        op[k] = ((unsigned long long)bd[k] << 32) | bi[k];
}

// ---------------- kNN phase 2: merge SEG_ sorted 8-lists ----------------
__global__ __launch_bounds__(128) void knn_merge(const unsigned long long* __restrict__ part,
                                                 int* __restrict__ src) {
    int q = blockIdx.x * 128 + threadIdx.x;
    int b = q / N_;
    unsigned long long best[K_];
#pragma unroll
    for (int k = 0; k < K_; ++k) best[k] = ~0ull;
    for (int s = 0; s < SEG_; ++s) {
        const unsigned long long* lp = part + ((size_t)s * BN_ + q) * K_;
#pragma unroll
        for (int k = 0; k < K_; ++k) {
            unsigned long long key = lp[k];
            if (key >= best[K_-1]) break;
            unsigned long long cur = key;
#pragma unroll
            for (int p = 0; p < K_; ++p) {
                unsigned long long lo = best[p] < cur ? best[p] : cur;
                unsigned long long hi = best[p] < cur ? cur : best[p];
                best[p] = lo; cur = hi;
            }
        }
    }
#pragma unroll
    for (int k = 0; k < K_; ++k)
        src[(size_t)q*K_ + k] = b*N_ + (int)(best[k] & 0xFFFFFFFFu);
}

// ---------------- fused: layer-1 input cast + P4 pack + layer-1 weight prep ----------------
__global__ __launch_bounds__(256) void cast_prep1(const float* __restrict__ X,
                                                  unsigned short* __restrict__ Xh,
                                                  unsigned short* __restrict__ Xl,
                                                  float4* __restrict__ P4,
                                                  const float* __restrict__ W1,
                                                  unsigned short* __restrict__ WTh,
                                                  unsigned short* __restrict__ WTl) {
    const int total8 = BN_ * 32 / 8;     // 65536
    int t = blockIdx.x * 256 + threadIdx.x;
    if (t < total8) {
        int m = t >> 2;
        int k0 = (t & 3) * 8;
        ushort8_ vh, vl;
#pragma unroll
        for (int j = 0; j < 8; ++j) {
            int k = k0 + j;
            float v = (k < IN_) ? X[(size_t)m*IN_ + k] : 0.0f;
            unsigned short h = f2bf(v);
            vh[j] = h;
            vl[j] = f2bf(v - bf2f(h));
        }
        *(ushort8_*)(Xh + (size_t)m*32 + k0) = vh;
        *(ushort8_*)(Xl + (size_t)m*32 + k0) = vl;
        if (t < BN_) {
            const float* p = X + (size_t)t*IN_;
            float x = p[0], y = p[1], z = p[2];
            P4[t] = make_float4(x, y, z, x*x + y*y + z*z);
        }
    } else {
        int idx = t - total8;
        const int nWT = 2*64*32;         // 4096
        if (idx < nWT) {
            int n = idx >> 5;
            int k = idx & 31;
            float val = 0.0f;
            if (k < IN_) {
                if (n < 64) val = W1[(size_t)k*64 + n] - W1[(size_t)(IN_+k)*64 + n];
                else        val = W1[(size_t)(IN_+k)*64 + (n - 64)];
            }
            unsigned short h = f2bf(val);
            WTh[(size_t)n*32 + k] = h;
            WTl[(size_t)n*32 + k] = f2bf(val - bf2f(h));
        }
    }
}

// ---------------- fused BN-reduce + next-layer weight prep ----------------
// grid = Cprev blocks; block k: reduce partial column k -> sc/sh; write WT column k of next layer
__global__ __launch_bounds__(256) void bnprep(const float* __restrict__ partial, int nblocks, int Cprev,
                                              const float* __restrict__ g, const float* __restrict__ be,
                                              float* __restrict__ scale, float* __restrict__ shift,
                                              const float* __restrict__ W, int C, int Kpad,
                                              unsigned short* __restrict__ WTh,
                                              unsigned short* __restrict__ WTl) {
    int k = blockIdx.x;
    int t = threadIdx.x;
    float s0 = 0.f, s1 = 0.f;
    for (int blk = t; blk < nblocks; blk += 256) {
        s0 += partial[(size_t)blk*2*Cprev + k];
        s1 += partial[(size_t)blk*2*Cprev + Cprev + k];
    }
    __shared__ float l0[256], l1[256];
    __shared__ float sc_s;
    l0[t] = s0; l1[t] = s1;
    __syncthreads();
    for (int off = 128; off > 0; off >>= 1) {
        if (t < off) { l0[t] += l0[t + off]; l1[t] += l1[t + off]; }
        __syncthreads();
    }
    if (t == 0) {
        float mean = l0[0] / (float)NEDGE_;
        float var  = l1[0] / (float)NEDGE_ - mean*mean;
        float sc = g[k] * rsqrtf(var + 1e-5f);
        scale[k] = sc;
        shift[k] = be[k] - mean*sc;
        sc_s = sc;
    }
    __syncthreads();
    float s = sc_s;
    // write WT column k (Kpad == Cprev for layers 2/3 -> no zero padding needed)
    for (int n = t; n < 2*C; n += 256) {
        float val;
        if (n < C) val = s * (W[(size_t)k*C + n] - W[(size_t)(Cprev+k)*C + n]);
        else       val = s * W[(size_t)(Cprev+k)*C + (n - C)];
        unsigned short h = f2bf(val);
        WTh[(size_t)n*Kpad + k] = h;
        WTl[(size_t)n*Kpad + k] = f2bf(val - bf2f(h));
    }
}

// ---------------- plain BN reduce (layer 3 -> gmax affine only) ----------------
__global__ __launch_bounds__(256) void reduce_kernel(const float* __restrict__ partial, int nblocks, int C,
                              const float* __restrict__ g, const float* __restrict__ be,
                              float* __restrict__ scale, float* __restrict__ shift) {
    int c = blockIdx.x;
    float s0 = 0.f, s1 = 0.f;
    for (int blk = threadIdx.x; blk < nblocks; blk += 256) {
        s0 += partial[(size_t)blk*2*C + c];
        s1 += partial[(size_t)blk*2*C + C + c];
    }
    __shared__ float l0[256], l1[256];
    l0[threadIdx.x] = s0; l1[threadIdx.x] = s1;
    __syncthreads();
    for (int off = 128; off > 0; off >>= 1) {
        if (threadIdx.x < off) {
            l0[threadIdx.x] += l0[threadIdx.x + off];
            l1[threadIdx.x] += l1[threadIdx.x + off];
        }
        __syncthreads();
    }
    if (threadIdx.x == 0) {
        float mean = l0[0] / (float)NEDGE_;
        float var  = l1[0] / (float)NEDGE_ - mean*mean;
        float sc = g[c] * rsqrtf(var + 1e-5f);
        scale[c] = sc;
        shift[c] = be[c] - mean*sc;
    }
}

// ---------------- split-bf16 MFMA GEMM: PQ[M][Ntot] = X[M][K] @ WT^T, 128x128 tile, BK=32 ----------------
__global__ __launch_bounds__(256) void mfma_dual(const unsigned short* __restrict__ Xh,
                                                 const unsigned short* __restrict__ Xl,
                                                 const unsigned short* __restrict__ WTh,
                                                 const unsigned short* __restrict__ WTl,
                                                 float* __restrict__ PQ, int K, int Ntot,
                                                 int gx) {
    __shared__ unsigned short sXh[128*32], sXl[128*32], sWh[128*32], sWl[128*32];
    int n = blockIdx.x;
    int by = (n & 7) + 8*(n/(8*gx));    // y%8 == n%8 == XCD
    int bx = (n >> 3) % gx;
    int tid = threadIdx.x, l = tid & 63, w = tid >> 6;
    int wr = w >> 1, wc = w & 1;
    int bm = by * 128, bn0 = bx * 128;

    f32x4_ acc[4][4];
#pragma unroll
    for (int i = 0; i < 4; ++i)
#pragma unroll
        for (int j = 0; j < 4; ++j) acc[i][j] = (f32x4_){0.f, 0.f, 0.f, 0.f};

    for (int k0 = 0; k0 < K; k0 += 32) {
#pragma unroll
        for (int i = 0; i < 2; ++i) {
            int idx = tid + i*256;
            int row = idx >> 2;
            int col0 = (idx & 3) * 8;
            size_t gxo = (size_t)(bm  + row)*K + k0 + col0;
            size_t gwo = (size_t)(bn0 + row)*K + k0 + col0;
            int lo_ = ((row << 6) | (col0 << 1)) ^ ((row & 7) << 4);
            *(ushort8_*)((char*)sXh + lo_) = *(const ushort8_*)(Xh + gxo);
            *(ushort8_*)((char*)sXl + lo_) = *(const ushort8_*)(Xl + gxo);
            *(ushort8_*)((char*)sWh + lo_) = *(const ushort8_*)(WTh + gwo);
            *(ushort8_*)((char*)sWl + lo_) = *(const ushort8_*)(WTl + gwo);
        }
        __syncthreads();

        int kb = (l >> 4) << 4;
        bf16x8_ bh[4], bl4[4];
#pragma unroll
        for (int nf = 0; nf < 4; ++nf) {
            int rn = wc*64 + nf*16 + (l & 15);
            int o = ((rn << 6) | kb) ^ ((rn & 7) << 4);
            bh[nf]  = *(const bf16x8_*)((const char*)sWh + o);
            bl4[nf] = *(const bf16x8_*)((const char*)sWl + o);
        }
#pragma unroll
        for (int mf = 0; mf < 4; ++mf) {
            int rm = wr*64 + mf*16 + (l & 15);
            int o = ((rm << 6) | kb) ^ ((rm & 7) << 4);
            bf16x8_ ah = *(const bf16x8_*)((const char*)sXh + o);
            bf16x8_ al = *(const bf16x8_*)((const char*)sXl + o);
#pragma unroll
            for (int nf = 0; nf < 4; ++nf) {
                acc[mf][nf] = __builtin_amdgcn_mfma_f32_16x16x32_bf16(ah, bh[nf],  acc[mf][nf], 0, 0, 0);
                acc[mf][nf] = __builtin_amdgcn_mfma_f32_16x16x32_bf16(ah, bl4[nf], acc[mf][nf], 0, 0, 0);
                acc[mf][nf] = __builtin_amdgcn_mfma_f32_16x16x32_bf16(al, bh[nf],  acc[mf][nf], 0, 0, 0);
            }
        }
        __syncthreads();
    }

    int r0 = (l >> 4) << 2, cB = l & 15;
#pragma unroll
    for (int mf = 0; mf < 4; ++mf)
#pragma unroll
        for (int nf = 0; nf < 4; ++nf) {
            int col = bn0 + wc*64 + nf*16 + cB;
#pragma unroll
            for (int reg = 0; reg < 4; ++reg) {
                int row = bm + wr*64 + mf*16 + r0 + reg;
                PQ[(size_t)row*Ntot + col] = acc[mf][nf][reg];
            }
        }
}

// ---------------- edge combine (256 thr, NG channel-groups): inline cvec; h=P+Q+cv; lrelu;
//                  per-dst max -> split-bf16; LDS cross-group fold for BN partials + block max ----------------
__global__ __launch_bounds__(256) void combine_kernel(
        const float* __restrict__ P, const float* __restrict__ Q,
        const int* __restrict__ src,
        unsigned short* __restrict__ Xh_out, unsigned short* __restrict__ Xl_out,
        float* __restrict__ partial, float* __restrict__ gpart,
        const float* __restrict__ W, const float* __restrict__ bias,
        const float* __restrict__ shift, int Cin,
        int C, int S) {
    int pb = blockIdx.x;
    int lb = (pb & 7) * CHUNKS_ + (pb >> 3);   // XCD swizzle: batch (pb&7) -> XCD (pb&7)
    int tid = threadIdx.x;
    int c = tid & (C - 1);
    int g = tid / C;                     // channel-group id, NG = 256/C groups
    int PPG = GRP / (256 / C);           // points per group: L1 2, L2 4, L3 8
    // inline cvec: cv = bias + shift_prev @ W_top (coalesced across c; W L2-resident)
    float cv = bias[c];
    if (shift)
        for (int d = 0; d < Cin; ++d) cv += shift[d] * W[(size_t)d*C + c];

    int i0 = lb * GRP + g * PPG;
    float sum = 0.f, ssq = 0.f;
    float bmx = -INFINITY;
    for (int gg = 0; gg < PPG; ++gg) {
        int i = i0 + gg;
        float p = P[(size_t)i*S + c] + cv;
        float mx = -INFINITY;
#pragma unroll
        for (int k = 0; k < K_; ++k) {
            int s = src[(size_t)i*K_ + k];
            float h = p + Q[(size_t)s*S + c];
            float l = (h >= 0.f) ? h : 0.2f*h;
            sum += l; ssq += l*l;
            mx = fmaxf(mx, l);
        }
        if (Xh_out) {
            unsigned short hh = f2bf(mx);
            Xh_out[(size_t)i*C + c] = hh;
            Xl_out[(size_t)i*C + c] = f2bf(mx - bf2f(hh));
        }
        bmx = fmaxf(bmx, mx);
    }
    __shared__ float s0[256], s1[256], s2[256];
    s0[tid] = sum; s1[tid] = ssq; s2[tid] = bmx;
    __syncthreads();
    for (int off = 128; off >= C; off >>= 1) {
        if (tid < off) {
            s0[tid] += s0[tid + off];
            s1[tid] += s1[tid + off];
            s2[tid] = fmaxf(s2[tid], s2[tid + off]);
        }
        __syncthreads();
    }
    if (tid < C) {
        gpart[(size_t)lb*C + c] = s2[tid];
        partial[(size_t)lb*2*C + c]     = s0[tid];
        partial[(size_t)lb*2*C + C + c] = s1[tid];
    }
}

// ---------------- fused global max-pool finalize ----------------
__global__ __launch_bounds__(1024) void gmax_finalize(
        const float* __restrict__ gp1, const float* __restrict__ gp2, const float* __restrict__ gp3,
        const float* __restrict__ sc1, const float* __restrict__ sh1,
        const float* __restrict__ sc2, const float* __restrict__ sh2,
        const float* __restrict__ sc3, const float* __restrict__ sh3,
        float* __restrict__ gfeat) {
    int b = blockIdx.x, grp = blockIdx.y;
    const float *gp, *sc, *sh; int C, c0, coff;
    if (grp == 0)      { gp = gp1; sc = sc1; sh = sh1; C = 64;  c0 = 0;            coff = 0;   }
    else if (grp <= 2) { gp = gp2; sc = sc2; sh = sh2; C = 128; c0 = (grp-1)*64;   coff = 64;  }
    else               { gp = gp3; sc = sc3; sh = sh3; C = 256; c0 = (grp-3)*64;   coff = 192; }
    int cl = threadIdx.x & 63;
    int stripe = threadIdx.x >> 6;   // 0..15
    int c = c0 + cl;
    float mx = -INFINITY;
    for (int ch = stripe; ch < CHUNKS_; ch += 16)
        mx = fmaxf(mx, gp[((size_t)b*CHUNKS_ + ch)*C + c]);
    __shared__ float red[16][64];
    red[stripe][cl] = mx;
    __syncthreads();
    for (int off = 8; off > 0; off >>= 1) {
        if (stripe < off) red[stripe][cl] = fmaxf(red[stripe][cl], red[stripe+off][cl]);
        __syncthreads();
    }
    if (stripe == 0)
        gfeat[b*448 + coff + c] = sc[c]*red[0][cl] + sh[c];
}

// ---------------- head part 1: H = BN(lrelu(gfeat@Wf1 + bf1)) ----------------
__global__ __launch_bounds__(256) void final1(const float* __restrict__ gfeat,
                                              const float* __restrict__ Wf1, const float* __restrict__ bf1,
                                              const float* __restrict__ gf, const float* __restrict__ bef,
                                              float* __restrict__ H) {
    __shared__ float gfs[B_][448];
    __shared__ float red[4][64][B_];
    int t = threadIdx.x;
    int cl = t & 63;
    int stripe = t >> 6;
    int c = blockIdx.x * 64 + cl;
    for (int e = t; e < B_*448; e += 256) gfs[e/448][e%448] = gfeat[e];
    __syncthreads();
    float acc[B_] = {};
    for (int d = stripe*112; d < stripe*112 + 112; ++d) {
        float w = Wf1[(size_t)d*512 + c];
#pragma unroll
        for (int r = 0; r < B_; ++r) acc[r] += gfs[r][d] * w;
    }
#pragma unroll
    for (int r = 0; r < B_; ++r) red[stripe][cl][r] = acc[r];
    __syncthreads();
    if (stripe == 0) {
        float v[B_];
        float b1v = bf1[c];
#pragma unroll
        for (int r = 0; r < B_; ++r) {
            float a = red[0][cl][r] + red[1][cl][r] + red[2][cl][r] + red[3][cl][r] + b1v;
            v[r] = (a >= 0.f) ? a : 0.2f*a;
        }
        float mean = 0.f;
#pragma unroll
        for (int r = 0; r < B_; ++r) mean += v[r];
        mean *= (1.0f/B_);
        float var = 0.f;
#pragma unroll
        for (int r = 0; r < B_; ++r) { float dd = v[r] - mean; var += dd*dd; }
        var *= (1.0f/B_);
        float sc = gf[c] * rsqrtf(var + 1e-5f);
        float sh = bef[c] - mean*sc;
#pragma unroll
        for (int r = 0; r < B_; ++r) H[(size_t)r*512 + c] = v[r]*sc + sh;
    }
}

// ---------------- head part 2: out = H @ Wf2 + bf2 ----------------
__global__ __launch_bounds__(128) void final2(const float* __restrict__ H,
                                              const float* __restrict__ Wf2, const float* __restrict__ bf2,
                                              float* __restrict__ out) {
    int b = blockIdx.x, c = threadIdx.x;
    __shared__ float hs[512];
    for (int e = c; e < 512; e += 128) hs[e] = H[(size_t)b*512 + e];
    __syncthreads();
    float a = bf2[c];
    for (int d = 0; d < 512; ++d) a += hs[d] * Wf2[(size_t)d*128 + c];
    out[b*128 + c] = a;
}

// ---------------- host side ----------------
extern "C" void kernel_launch(void* const* d_in, const int* in_sizes, int n_in,
                              void* d_out, int out_size, void* d_ws, size_t ws_size,
                              hipStream_t stream) {
    (void)in_sizes; (void)n_in; (void)out_size; (void)ws_size;
    const float* points = (const float*)d_in[0];
    const float* W1 = (const float*)d_in[1];  const float* b1 = (const float*)d_in[2];
    const float* g1 = (const float*)d_in[3];  const float* be1 = (const float*)d_in[4];
    const float* W2 = (const float*)d_in[5];  const float* b2 = (const float*)d_in[6];
    const float* g2 = (const float*)d_in[7];  const float* be2 = (const float*)d_in[8];
    const float* W3 = (const float*)d_in[9];  const float* b3 = (const float*)d_in[10];
    const float* g3 = (const float*)d_in[11]; const float* be3 = (const float*)d_in[12];
    const float* Wf1 = (const float*)d_in[13]; const float* bf1 = (const float*)d_in[14];
    const float* gf = (const float*)d_in[15];  const float* bef = (const float*)d_in[16];
    const float* Wf2 = (const float*)d_in[17]; const float* bf2 = (const float*)d_in[18];
    float* out = (float*)d_out;

    size_t off = 0;
    char* base = (char*)d_ws;
    auto carve = [&](size_t bytes) -> void* {
        void* p = base + off;
        off += (bytes + 255) & ~(size_t)255;
        return p;
    };
    int*   src     = (int*)  carve((size_t)NEDGE_ * 4);
    float* PQ      = (float*)carve((size_t)BN_ * 512 * 4);   // 32MB; also kNN partial overlay
    float* gp1     = (float*)carve((size_t)(BN_/GRP) * 64 * 4);
    float* gp2     = (float*)carve((size_t)(BN_/GRP) * 128 * 4);
    float* gp3     = (float*)carve((size_t)(BN_/GRP) * 256 * 4);
    unsigned short* XhA = (unsigned short*)carve((size_t)BN_ * 128 * 2);
    unsigned short* XlA = (unsigned short*)carve((size_t)BN_ * 128 * 2);
    unsigned short* XhB = (unsigned short*)carve((size_t)BN_ * 128 * 2);
    unsigned short* XlB = (unsigned short*)carve((size_t)BN_ * 128 * 2);
    unsigned short* WTh = (unsigned short*)carve((size_t)512 * 128 * 2);
    unsigned short* WTl = (unsigned short*)carve((size_t)512 * 128 * 2);
    float4* P4     = (float4*)carve((size_t)BN_ * 16);
    float* sc1     = (float*)carve(64 * 4);
    float* sh1     = (float*)carve(64 * 4);
    float* sc2     = (float*)carve(128 * 4);
    float* sh2     = (float*)carve(128 * 4);
    float* sc3     = (float*)carve(256 * 4);
    float* sh3     = (float*)carve(256 * 4);
    float* partial = (float*)carve((size_t)(BN_/GRP) * 2 * 256 * 4);
    float* gfeat   = (float*)carve((size_t)B_ * 448 * 4);
    float* H       = (float*)carve((size_t)B_ * 512 * 4);

    // fused: cast layer-1 input + P4 pack + layer-1 WT prep
    cast_prep1<<<(65536 + 4096 + 255)/256, 256, 0, stream>>>(
        points, XhA, XlA, P4, W1, WTh, WTl);

    // kNN: phase-1 partials (32MB) overlay PQ (dead until first mfma_dual)
    unsigned long long* part = (unsigned long long*)PQ;
    knn_part<<<dim3(BN_/256, SEG_), 256, 0, stream>>>(P4, part);
    knn_merge<<<BN_/128, 128, 0, stream>>>(part, src);

    // ---- layer 1 ----
    mfma_dual<<<1*(BN_/128), 256, 0, stream>>>(XhA, XlA, WTh, WTl, PQ, 32, 128, 1);
    combine_kernel<<<BN_/GRP, 256, 0, stream>>>(PQ, PQ + 64, src, XhB, XlB, partial, gp1,
                                                W1, b1, nullptr, IN_, 64, 128);
    // ---- bnprep: reduce L1 stats + prep L2 weights ----
    bnprep<<<64, 256, 0, stream>>>(partial, BN_/GRP, 64, g1, be1, sc1, sh1,
                                   W2, 128, 64, WTh, WTl);
    // ---- layer 2 ----
    mfma_dual<<<2*(BN_/128), 256, 0, stream>>>(XhB, XlB, WTh, WTl, PQ, 64, 256, 2);
    combine_kernel<<<BN_/GRP, 256, 0, stream>>>(PQ, PQ + 128, src, XhA, XlA, partial, gp2,
                                                W2, b2, sh1, 64, 128, 256);
    // ---- bnprep: reduce L2 stats + prep L3 weights ----
    bnprep<<<128, 256, 0, stream>>>(partial, BN_/GRP, 128, g2, be2, sc2, sh2,
                                    W3, 256, 128, WTh, WTl);
    // ---- layer 3 ----
    mfma_dual<<<4*(BN_/128), 256, 0, stream>>>(XhA, XlA, WTh, WTl, PQ, 128, 512, 4);
    combine_kernel<<<BN_/GRP, 256, 0, stream>>>(PQ, PQ + 256, src, nullptr, nullptr, partial, gp3,
                                                W3, b3, sh2, 128, 256, 512);
    reduce_kernel<<<256, 256, 0, stream>>>(partial, BN_/GRP, 256, g3, be3, sc3, sh3);

    gmax_finalize<<<dim3(B_, 7), 1024, 0, stream>>>(gp1, gp2, gp3,
                                                    sc1, sh1, sc2, sh2, sc3, sh3, gfeat);

    final1<<<8, 256, 0, stream>>>(gfeat, Wf1, bf1, gf, bef, H);
    final2<<<8, 128, 0, stream>>>(H, Wf2, bf2, out);
}

// Round 12
// 219.640 us; speedup vs baseline: 1.1230x; 1.1230x over previous
//
#include <hip/hip_runtime.h>
#include <math.h>

#define B_ 8
#define N_ 2048
#define K_ 8
#define IN_ 5
#define BN_ (B_*N_)
#define NEDGE_ (BN_*K_)
#define GRP 8
#define SEG_ 32
#define CSEG_ (N_/SEG_)   // 64 candidates per segment
#define CHUNKS_ (N_/GRP)  // 256 combine-blocks per batch

typedef unsigned short ushort8_ __attribute__((ext_vector_type(8)));
typedef short bf16x8_ __attribute__((ext_vector_type(8)));
typedef float f32x4_ __attribute__((ext_vector_type(4)));

__device__ inline unsigned short f2bf(float f) {
    unsigned int u = __float_as_uint(f);
    u += 0x7fffu + ((u >> 16) & 1u);
    return (unsigned short)(u >> 16);
}
__device__ inline float bf2f(unsigned short h) {
    return __uint_as_float(((unsigned int)h) << 16);
}

// ---------------- kNN phase 1: per-segment top-8; raw-bit keys (d>=0), scalar candidate loads ----------------
__global__ __launch_bounds__(256) void knn_part(const float4* __restrict__ P4,
                                                unsigned long long* __restrict__ part) {
    int tid = threadIdx.x;
    int bblk = blockIdx.x >> 3;         // batch id: provably uniform (8 blocks per batch)
    int q = blockIdx.x * 256 + tid;
    int nloc = q & (N_-1);
    int seg = blockIdx.y;

    float4 qp = P4[q];
    float qx2 = -2.0f*qp.x, qy2 = -2.0f*qp.y, qz2 = -2.0f*qp.z;
    float qsq = qp.w;

    unsigned int bd[K_], bi[K_];
#pragma unroll
    for (int k = 0; k < K_; ++k) { bd[k] = 0xFFFFFFFFu; bi[k] = 0xFFFFFFFFu; }

    const float4* __restrict__ cb = P4 + ((size_t)bblk << 11) + (size_t)seg*CSEG_;  // uniform -> s_load
    int jbase = seg * CSEG_;

#pragma unroll 8
    for (int jj = 0; jj < CSEG_; ++jj) {
        float4 c = cb[jj];
        float d = qsq + c.w;
        d = fmaf(qx2, c.x, d);
        d = fmaf(qy2, c.y, d);
        d = fmaf(qz2, c.z, d);
        // raw float bits monotone for d>=0 (min pairwise d^2 >> fp error margin)
        unsigned int cd = __float_as_uint(d);
        int jg = jbase + jj;
        cd = (jg == nloc) ? 0xFFFFFFFFu : cd;   // self-exclusion -> max key, always expelled
        unsigned int ci = (unsigned int)jg;
        // stable unconditional insert: strict < keeps equal-d entries in idx (scan) order
#pragma unroll
        for (int p = 0; p < K_; ++p) {
            bool lt = cd < bd[p];
            unsigned int nd = lt ? cd : bd[p];
            unsigned int xd = lt ? bd[p] : cd;
            unsigned int ni = lt ? ci : bi[p];
            unsigned int xi = lt ? bi[p] : ci;
            bd[p] = nd; cd = xd; bi[p] = ni; ci = xi;
        }
    }
    unsigned long long* op = part + ((size_t)seg * BN_ + q) * K_;
#pragma unroll
    for (int k = 0; k < K_; ++k)
        op[k] = ((unsigned long long)bd[k] << 32) | bi[k];
}

// ---------------- kNN phase 2: merge SEG_ sorted 8-lists ----------------
__global__ __launch_bounds__(128) void knn_merge(const unsigned long long* __restrict__ part,
                                                 int* __restrict__ src) {
    int q = blockIdx.x * 128 + threadIdx.x;
    int b = q / N_;
    unsigned long long best[K_];
#pragma unroll
    for (int k = 0; k < K_; ++k) best[k] = ~0ull;
    for (int s = 0; s < SEG_; ++s) {
        const unsigned long long* lp = part + ((size_t)s * BN_ + q) * K_;
#pragma unroll
        for (int k = 0; k < K_; ++k) {
            unsigned long long key = lp[k];
            if (key >= best[K_-1]) break;
            unsigned long long cur = key;
#pragma unroll
            for (int p = 0; p < K_; ++p) {
                unsigned long long lo = best[p] < cur ? best[p] : cur;
                unsigned long long hi = best[p] < cur ? cur : best[p];
                best[p] = lo; cur = hi;
            }
        }
    }
#pragma unroll
    for (int k = 0; k < K_; ++k)
        src[(size_t)q*K_ + k] = b*N_ + (int)(best[k] & 0xFFFFFFFFu);
}

// ---------------- fused: layer-1 input cast + P4 pack + layer-1 weight prep + cvec1 ----------------
__global__ __launch_bounds__(256) void cast_prep1(const float* __restrict__ X,
                                                  unsigned short* __restrict__ Xh,
                                                  unsigned short* __restrict__ Xl,
                                                  float4* __restrict__ P4,
                                                  const float* __restrict__ W1,
                                                  const float* __restrict__ b1,
                                                  unsigned short* __restrict__ WTh,
                                                  unsigned short* __restrict__ WTl,
                                                  float* __restrict__ cvec) {
    const int total8 = BN_ * 32 / 8;     // 65536 (multiple of 256)
    int t = blockIdx.x * 256 + threadIdx.x;
    if (t < total8) {
        int m = t >> 2;                  // Kpad=32 -> 4 ushort8 per row
        int k0 = (t & 3) * 8;
        ushort8_ vh, vl;
#pragma unroll
        for (int j = 0; j < 8; ++j) {
            int k = k0 + j;
            float v = (k < IN_) ? X[(size_t)m*IN_ + k] : 0.0f;
            unsigned short h = f2bf(v);
            vh[j] = h;
            vl[j] = f2bf(v - bf2f(h));
        }
        *(ushort8_*)(Xh + (size_t)m*32 + k0) = vh;
        *(ushort8_*)(Xl + (size_t)m*32 + k0) = vl;
        if (t < BN_) {
            const float* p = X + (size_t)t*IN_;
            float x = p[0], y = p[1], z = p[2];
            P4[t] = make_float4(x, y, z, x*x + y*y + z*z);
        }
    } else {
        int idx = t - total8;
        const int nWT = 2*64*32;         // 4096 (multiple of 256)
        if (idx < nWT) {
            int n = idx >> 5;            // row in WT (0..127)
            int k = idx & 31;
            float val = 0.0f;
            if (k < IN_) {
                if (n < 64) val = W1[(size_t)k*64 + n] - W1[(size_t)(IN_+k)*64 + n];
                else        val = W1[(size_t)(IN_+k)*64 + (n - 64)];
            }
            unsigned short h = f2bf(val);
            WTh[(size_t)n*32 + k] = h;
            WTl[(size_t)n*32 + k] = f2bf(val - bf2f(h));
        } else if (idx < nWT + 64) {
            int c = idx - nWT;
            cvec[c] = b1[c];             // layer 1: no BN shift folding
        }
    }
}

// ---------------- fused weight prep (layers 2,3): WT split-bf16 (BN fold) + c' vector ----------------
__global__ __launch_bounds__(256) void prep_layer(const float* __restrict__ W,
                                                  const float* __restrict__ scale,
                                                  const float* __restrict__ shift,
                                                  const float* __restrict__ bias,
                                                  unsigned short* __restrict__ WTh,
                                                  unsigned short* __restrict__ WTl,
                                                  float* __restrict__ cvec,
                                                  int Cin, int C, int Kpad) {
    int idx = blockIdx.x * 256 + threadIdx.x;
    int nWT = 2*C*Kpad;
    if (idx < nWT) {
        int n = idx / Kpad;
        int k = idx % Kpad;
        float val = 0.0f;
        if (k < Cin) {
            float s = scale[k];
            if (n < C) val = s * (W[(size_t)k*C + n] - W[(size_t)(Cin+k)*C + n]);
            else       val = s * W[(size_t)(Cin+k)*C + (n - C)];
        }
        unsigned short h = f2bf(val);
        WTh[(size_t)n*Kpad + k] = h;
        WTl[(size_t)n*Kpad + k] = f2bf(val - bf2f(h));
    } else if (idx < nWT + C) {
        int c = idx - nWT;
        float acc = bias[c];
        for (int d = 0; d < Cin; ++d) acc += shift[d] * W[(size_t)d*C + c];
        cvec[c] = acc;
    }
}

// ---------------- split-bf16 MFMA GEMM: PQ[M][Ntot] = X[M][K] @ WT^T, 128x128 tile, BK=32 ----------------
// 1-D grid, XCD-swizzled: all col-blocks of a row-panel land on XCD (y%8) for A-panel L2 reuse
__global__ __launch_bounds__(256) void mfma_dual(const unsigned short* __restrict__ Xh,
                                                 const unsigned short* __restrict__ Xl,
                                                 const unsigned short* __restrict__ WTh,
                                                 const unsigned short* __restrict__ WTl,
                                                 float* __restrict__ PQ, int K, int Ntot,
                                                 int gx) {
    __shared__ unsigned short sXh[128*32], sXl[128*32], sWh[128*32], sWl[128*32];
    int n = blockIdx.x;
    int by = (n & 7) + 8*(n/(8*gx));    // y%8 == n%8 == XCD
    int bx = (n >> 3) % gx;
    int tid = threadIdx.x, l = tid & 63, w = tid >> 6;
    int wr = w >> 1, wc = w & 1;
    int bm = by * 128, bn0 = bx * 128;

    f32x4_ acc[4][4];
#pragma unroll
    for (int i = 0; i < 4; ++i)
#pragma unroll
        for (int j = 0; j < 4; ++j) acc[i][j] = (f32x4_){0.f, 0.f, 0.f, 0.f};

    for (int k0 = 0; k0 < K; k0 += 32) {
#pragma unroll
        for (int i = 0; i < 2; ++i) {
            int idx = tid + i*256;
            int row = idx >> 2;
            int col0 = (idx & 3) * 8;
            size_t gxo = (size_t)(bm  + row)*K + k0 + col0;
            size_t gwo = (size_t)(bn0 + row)*K + k0 + col0;
            int lo_ = ((row << 6) | (col0 << 1)) ^ ((row & 7) << 4);
            *(ushort8_*)((char*)sXh + lo_) = *(const ushort8_*)(Xh + gxo);
            *(ushort8_*)((char*)sXl + lo_) = *(const ushort8_*)(Xl + gxo);
            *(ushort8_*)((char*)sWh + lo_) = *(const ushort8_*)(WTh + gwo);
            *(ushort8_*)((char*)sWl + lo_) = *(const ushort8_*)(WTl + gwo);
        }
        __syncthreads();

        int kb = (l >> 4) << 4;
        bf16x8_ bh[4], bl4[4];
#pragma unroll
        for (int nf = 0; nf < 4; ++nf) {
            int rn = wc*64 + nf*16 + (l & 15);
            int o = ((rn << 6) | kb) ^ ((rn & 7) << 4);
            bh[nf]  = *(const bf16x8_*)((const char*)sWh + o);
            bl4[nf] = *(const bf16x8_*)((const char*)sWl + o);
        }
#pragma unroll
        for (int mf = 0; mf < 4; ++mf) {
            int rm = wr*64 + mf*16 + (l & 15);
            int o = ((rm << 6) | kb) ^ ((rm & 7) << 4);
            bf16x8_ ah = *(const bf16x8_*)((const char*)sXh + o);
            bf16x8_ al = *(const bf16x8_*)((const char*)sXl + o);
#pragma unroll
            for (int nf = 0; nf < 4; ++nf) {
                acc[mf][nf] = __builtin_amdgcn_mfma_f32_16x16x32_bf16(ah, bh[nf],  acc[mf][nf], 0, 0, 0);
                acc[mf][nf] = __builtin_amdgcn_mfma_f32_16x16x32_bf16(ah, bl4[nf], acc[mf][nf], 0, 0, 0);
                acc[mf][nf] = __builtin_amdgcn_mfma_f32_16x16x32_bf16(al, bh[nf],  acc[mf][nf], 0, 0, 0);
            }
        }
        __syncthreads();
    }

    int r0 = (l >> 4) << 2, cB = l & 15;
#pragma unroll
    for (int mf = 0; mf < 4; ++mf)
#pragma unroll
        for (int nf = 0; nf < 4; ++nf) {
            int col = bn0 + wc*64 + nf*16 + cB;
#pragma unroll
            for (int reg = 0; reg < 4; ++reg) {
                int row = bm + wr*64 + mf*16 + r0 + reg;
                PQ[(size_t)row*Ntot + col] = acc[mf][nf][reg];
            }
        }
}

// ---------------- edge combine: h = P[dst] + Q[src] + cvec ; lrelu; per-dst max -> split-bf16 X_next;
//                  BN partials (per-block stores); per-block partial max. blockDim = C ----------------
__global__ void combine_kernel(const float* __restrict__ P, const float* __restrict__ Q,
                               const float* __restrict__ cvec, const int* __restrict__ src,
                               unsigned short* __restrict__ Xh_out, unsigned short* __restrict__ Xl_out,
                               float* __restrict__ partial, float* __restrict__ gpart,
                               int C, int S) {
    int pb = blockIdx.x;
    int lb = (pb & 7) * CHUNKS_ + (pb >> 3);   // bijective: XCD (pb%8) gets all blocks of batch pb%8
    int c = threadIdx.x;                 // blockDim.x == C
    int i0 = lb * GRP;
    float cv = cvec[c];
    float sum = 0.f, ssq = 0.f;
    float bmx = -INFINITY;
    for (int g = 0; g < GRP; ++g) {
        int i = i0 + g;
        float p = P[(size_t)i*S + c] + cv;
        float mx = -INFINITY;
#pragma unroll
        for (int k = 0; k < K_; ++k) {
            int s = src[(size_t)i*K_ + k];
            float h = p + Q[(size_t)s*S + c];
            float l = (h >= 0.f) ? h : 0.2f*h;
            sum += l; ssq += l*l;
            mx = fmaxf(mx, l);
        }
        if (Xh_out) {                    // next layer's input, split-bf16 (Kpad_next == C)
            unsigned short hh = f2bf(mx);
            Xh_out[(size_t)i*C + c] = hh;
            Xl_out[(size_t)i*C + c] = f2bf(mx - bf2f(hh));
        }
        bmx = fmaxf(bmx, mx);
    }
    gpart[(size_t)lb*C + c] = bmx;
    partial[(size_t)lb*2*C + c]     = sum;
    partial[(size_t)lb*2*C + C + c] = ssq;
}

// ---------------- BN stats reduce -> scale/shift (deterministic tree) ----------------
__global__ __launch_bounds__(256) void reduce_kernel(const float* __restrict__ partial, int nblocks, int C,
                              const float* __restrict__ g, const float* __restrict__ be,
                              float* __restrict__ scale, float* __restrict__ shift) {
    int c = blockIdx.x;
    float s0 = 0.f, s1 = 0.f;
    for (int blk = threadIdx.x; blk < nblocks; blk += 256) {
        s0 += partial[(size_t)blk*2*C + c];
        s1 += partial[(size_t)blk*2*C + C + c];
    }
    __shared__ float l0[256], l1[256];
    l0[threadIdx.x] = s0; l1[threadIdx.x] = s1;
    __syncthreads();
    for (int off = 128; off > 0; off >>= 1) {
        if (threadIdx.x < off) {
            l0[threadIdx.x] += l0[threadIdx.x + off];
            l1[threadIdx.x] += l1[threadIdx.x + off];
        }
        __syncthreads();
    }
    if (threadIdx.x == 0) {
        float mean = l0[0] / (float)NEDGE_;
        float var  = l1[0] / (float)NEDGE_ - mean*mean;
        float sc = g[c] * rsqrtf(var + 1e-5f);
        scale[c] = sc;
        shift[c] = be[c] - mean*sc;
    }
}

// ---------------- fused global max-pool finalize ----------------
__global__ __launch_bounds__(1024) void gmax_finalize(
        const float* __restrict__ gp1, const float* __restrict__ gp2, const float* __restrict__ gp3,
        const float* __restrict__ sc1, const float* __restrict__ sh1,
        const float* __restrict__ sc2, const float* __restrict__ sh2,
        const float* __restrict__ sc3, const float* __restrict__ sh3,
        float* __restrict__ gfeat) {
    int b = blockIdx.x, grp = blockIdx.y;
    const float *gp, *sc, *sh; int C, c0, coff;
    if (grp == 0)      { gp = gp1; sc = sc1; sh = sh1; C = 64;  c0 = 0;            coff = 0;   }
    else if (grp <= 2) { gp = gp2; sc = sc2; sh = sh2; C = 128; c0 = (grp-1)*64;   coff = 64;  }
    else               { gp = gp3; sc = sc3; sh = sh3; C = 256; c0 = (grp-3)*64;   coff = 192; }
    int cl = threadIdx.x & 63;
    int stripe = threadIdx.x >> 6;   // 0..15
    int c = c0 + cl;
    float mx = -INFINITY;
    for (int ch = stripe; ch < CHUNKS_; ch += 16)
        mx = fmaxf(mx, gp[((size_t)b*CHUNKS_ + ch)*C + c]);
    __shared__ float red[16][64];
    red[stripe][cl] = mx;
    __syncthreads();
    for (int off = 8; off > 0; off >>= 1) {
        if (stripe < off) red[stripe][cl] = fmaxf(red[stripe][cl], red[stripe+off][cl]);
        __syncthreads();
    }
    if (stripe == 0)
        gfeat[b*448 + coff + c] = sc[c]*red[0][cl] + sh[c];
}

// ---------------- head part 1: H = BN(lrelu(gfeat@Wf1 + bf1)) ----------------
__global__ __launch_bounds__(256) void final1(const float* __restrict__ gfeat,
                                              const float* __restrict__ Wf1, const float* __restrict__ bf1,
                                              const float* __restrict__ gf, const float* __restrict__ bef,
                                              float* __restrict__ H) {
    __shared__ float gfs[B_][448];
    __shared__ float red[4][64][B_];
    int t = threadIdx.x;
    int cl = t & 63;
    int stripe = t >> 6;
    int c = blockIdx.x * 64 + cl;
    for (int e = t; e < B_*448; e += 256) gfs[e/448][e%448] = gfeat[e];
    __syncthreads();
    float acc[B_] = {};
    for (int d = stripe*112; d < stripe*112 + 112; ++d) {
        float w = Wf1[(size_t)d*512 + c];
#pragma unroll
        for (int r = 0; r < B_; ++r) acc[r] += gfs[r][d] * w;
    }
#pragma unroll
    for (int r = 0; r < B_; ++r) red[stripe][cl][r] = acc[r];
    __syncthreads();
    if (stripe == 0) {
        float v[B_];
        float b1v = bf1[c];
#pragma unroll
        for (int r = 0; r < B_; ++r) {
            float a = red[0][cl][r] + red[1][cl][r] + red[2][cl][r] + red[3][cl][r] + b1v;
            v[r] = (a >= 0.f) ? a : 0.2f*a;
        }
        float mean = 0.f;
#pragma unroll
        for (int r = 0; r < B_; ++r) mean += v[r];
        mean *= (1.0f/B_);
        float var = 0.f;
#pragma unroll
        for (int r = 0; r < B_; ++r) { float dd = v[r] - mean; var += dd*dd; }
        var *= (1.0f/B_);
        float sc = gf[c] * rsqrtf(var + 1e-5f);
        float sh = bef[c] - mean*sc;
#pragma unroll
        for (int r = 0; r < B_; ++r) H[(size_t)r*512 + c] = v[r]*sc + sh;
    }
}

// ---------------- head part 2: out = H @ Wf2 + bf2 ----------------
__global__ __launch_bounds__(128) void final2(const float* __restrict__ H,
                                              const float* __restrict__ Wf2, const float* __restrict__ bf2,
                                              float* __restrict__ out) {
    int b = blockIdx.x, c = threadIdx.x;
    __shared__ float hs[512];
    for (int e = c; e < 512; e += 128) hs[e] = H[(size_t)b*512 + e];
    __syncthreads();
    float a = bf2[c];
    for (int d = 0; d < 512; ++d) a += hs[d] * Wf2[(size_t)d*128 + c];
    out[b*128 + c] = a;
}

// ---------------- host side ----------------
extern "C" void kernel_launch(void* const* d_in, const int* in_sizes, int n_in,
                              void* d_out, int out_size, void* d_ws, size_t ws_size,
                              hipStream_t stream) {
    (void)in_sizes; (void)n_in; (void)out_size; (void)ws_size;
    const float* points = (const float*)d_in[0];
    const float* W1 = (const float*)d_in[1];  const float* b1 = (const float*)d_in[2];
    const float* g1 = (const float*)d_in[3];  const float* be1 = (const float*)d_in[4];
    const float* W2 = (const float*)d_in[5];  const float* b2 = (const float*)d_in[6];
    const float* g2 = (const float*)d_in[7];  const float* be2 = (const float*)d_in[8];
    const float* W3 = (const float*)d_in[9];  const float* b3 = (const float*)d_in[10];
    const float* g3 = (const float*)d_in[11]; const float* be3 = (const float*)d_in[12];
    const float* Wf1 = (const float*)d_in[13]; const float* bf1 = (const float*)d_in[14];
    const float* gf = (const float*)d_in[15];  const float* bef = (const float*)d_in[16];
    const float* Wf2 = (const float*)d_in[17]; const float* bf2 = (const float*)d_in[18];
    float* out = (float*)d_out;

    size_t off = 0;
    char* base = (char*)d_ws;
    auto carve = [&](size_t bytes) -> void* {
        void* p = base + off;
        off += (bytes + 255) & ~(size_t)255;
        return p;
    };
    int*   src     = (int*)  carve((size_t)NEDGE_ * 4);
    float* PQ      = (float*)carve((size_t)BN_ * 512 * 4);   // 32MB; also kNN partial overlay
    float* gp1     = (float*)carve((size_t)(BN_/GRP) * 64 * 4);
    float* gp2     = (float*)carve((size_t)(BN_/GRP) * 128 * 4);
    float* gp3     = (float*)carve((size_t)(BN_/GRP) * 256 * 4);
    unsigned short* XhA = (unsigned short*)carve((size_t)BN_ * 128 * 2);
    unsigned short* XlA = (unsigned short*)carve((size_t)BN_ * 128 * 2);
    unsigned short* XhB = (unsigned short*)carve((size_t)BN_ * 128 * 2);
    unsigned short* XlB = (unsigned short*)carve((size_t)BN_ * 128 * 2);
    unsigned short* WTh = (unsigned short*)carve((size_t)512 * 128 * 2);
    unsigned short* WTl = (unsigned short*)carve((size_t)512 * 128 * 2);
    float4* P4     = (float4*)carve((size_t)BN_ * 16);
    float* cvec    = (float*)carve(256 * 4);
    float* sc1     = (float*)carve(64 * 4);
    float* sh1     = (float*)carve(64 * 4);
    float* sc2     = (float*)carve(128 * 4);
    float* sh2     = (float*)carve(128 * 4);
    float* sc3     = (float*)carve(256 * 4);
    float* sh3     = (float*)carve(256 * 4);
    float* partial = (float*)carve((size_t)(BN_/GRP) * 2 * 256 * 4);
    float* gfeat   = (float*)carve((size_t)B_ * 448 * 4);
    float* H       = (float*)carve((size_t)B_ * 512 * 4);

    // fused: cast layer-1 input + P4 pack + layer-1 weight prep + cvec1
    cast_prep1<<<(65536 + 4096 + 64 + 255)/256, 256, 0, stream>>>(
        points, XhA, XlA, P4, W1, b1, WTh, WTl, cvec);

    // kNN: phase-1 partials (32MB) overlay PQ (dead until first mfma_dual)
    unsigned long long* part = (unsigned long long*)PQ;
    knn_part<<<dim3(BN_/256, SEG_), 256, 0, stream>>>(P4, part);
    knn_merge<<<BN_/128, 128, 0, stream>>>(part, src);

    // ---- layer 1 (prep already done in cast_prep1) ----
    mfma_dual<<<1*(BN_/128), 256, 0, stream>>>(XhA, XlA, WTh, WTl, PQ, 32, 128, 1);
    combine_kernel<<<BN_/GRP, 64, 0, stream>>>(PQ, PQ + 64, cvec, src, XhB, XlB, partial, gp1, 64, 128);
    reduce_kernel<<<64, 256, 0, stream>>>(partial, BN_/GRP, 64, g1, be1, sc1, sh1);

    // ---- layer 2 ----
    prep_layer<<<(2*128*64 + 128 + 255)/256, 256, 0, stream>>>(W2, sc1, sh1, b2, WTh, WTl, cvec, 64, 128, 64);
    mfma_dual<<<2*(BN_/128), 256, 0, stream>>>(XhB, XlB, WTh, WTl, PQ, 64, 256, 2);
    combine_kernel<<<BN_/GRP, 128, 0, stream>>>(PQ, PQ + 128, cvec, src, XhA, XlA, partial, gp2, 128, 256);
    reduce_kernel<<<128, 256, 0, stream>>>(partial, BN_/GRP, 128, g2, be2, sc2, sh2);

    // ---- layer 3 ----
    prep_layer<<<(2*256*128 + 256 + 255)/256, 256, 0, stream>>>(W3, sc2, sh2, b3, WTh, WTl, cvec, 128, 256, 128);
    mfma_dual<<<4*(BN_/128), 256, 0, stream>>>(XhA, XlA, WTh, WTl, PQ, 128, 512, 4);
    combine_kernel<<<BN_/GRP, 256, 0, stream>>>(PQ, PQ + 256, cvec, src, nullptr, nullptr, partial, gp3, 256, 512);
    reduce_kernel<<<256, 256, 0, stream>>>(partial, BN_/GRP, 256, g3, be3, sc3, sh3);

    gmax_finalize<<<dim3(B_, 7), 1024, 0, stream>>>(gp1, gp2, gp3,
                                                    sc1, sh1, sc2, sh2, sc3, sh3, gfeat);

    final1<<<8, 256, 0, stream>>>(gfeat, Wf1, bf1, gf, bef, H);
    final2<<<8, 128, 0, stream>>>(H, Wf2, bf2, out);
}

// Round 13
// 214.169 us; speedup vs baseline: 1.1517x; 1.0255x over previous
//
#include <hip/hip_runtime.h>
#include <math.h>

#define B_ 8
#define N_ 2048
#define K_ 8
#define IN_ 5
#define BN_ (B_*N_)
#define NEDGE_ (BN_*K_)
#define SEG_ 32
#define CSEG_ (N_/SEG_)   // 64 candidates per segment

typedef unsigned short ushort8_ __attribute__((ext_vector_type(8)));
typedef unsigned short ushort4_ __attribute__((ext_vector_type(4)));
typedef short bf16x8_ __attribute__((ext_vector_type(8)));
typedef float f32x4_ __attribute__((ext_vector_type(4)));

__device__ inline unsigned short f2bf(float f) {
    unsigned int u = __float_as_uint(f);
    u += 0x7fffu + ((u >> 16) & 1u);
    return (unsigned short)(u >> 16);
}
__device__ inline float bf2f(unsigned short h) {
    return __uint_as_float(((unsigned int)h) << 16);
}

// ---------------- kNN phase 1: per-segment top-8; raw-bit keys (d>=0), scalar candidate loads ----------------
__global__ __launch_bounds__(256) void knn_part(const float4* __restrict__ P4,
                                                unsigned long long* __restrict__ part) {
    int tid = threadIdx.x;
    int bblk = blockIdx.x >> 3;         // batch id: provably uniform (8 blocks per batch)
    int q = blockIdx.x * 256 + tid;
    int nloc = q & (N_-1);
    int seg = blockIdx.y;

    float4 qp = P4[q];
    float qx2 = -2.0f*qp.x, qy2 = -2.0f*qp.y, qz2 = -2.0f*qp.z;
    float qsq = qp.w;

    unsigned int bd[K_], bi[K_];
#pragma unroll
    for (int k = 0; k < K_; ++k) { bd[k] = 0xFFFFFFFFu; bi[k] = 0xFFFFFFFFu; }

    const float4* __restrict__ cb = P4 + ((size_t)bblk << 11) + (size_t)seg*CSEG_;  // uniform -> s_load
    int jbase = seg * CSEG_;

#pragma unroll 8
    for (int jj = 0; jj < CSEG_; ++jj) {
        float4 c = cb[jj];
        float d = qsq + c.w;
        d = fmaf(qx2, c.x, d);
        d = fmaf(qy2, c.y, d);
        d = fmaf(qz2, c.z, d);
        unsigned int cd = __float_as_uint(d);   // monotone for d>=0
        int jg = jbase + jj;
        cd = (jg == nloc) ? 0xFFFFFFFFu : cd;   // self-exclusion -> max key, always expelled
        unsigned int ci = (unsigned int)jg;
#pragma unroll
        for (int p = 0; p < K_; ++p) {
            bool lt = cd < bd[p];
            unsigned int nd = lt ? cd : bd[p];
            unsigned int xd = lt ? bd[p] : cd;
            unsigned int ni = lt ? ci : bi[p];
            unsigned int xi = lt ? bi[p] : ci;
            bd[p] = nd; cd = xd; bi[p] = ni; ci = xi;
        }
    }
    unsigned long long* op = part + ((size_t)seg * BN_ + q) * K_;
#pragma unroll
    for (int k = 0; k < K_; ++k)
        op[k] = ((unsigned long long)bd[k] << 32) | bi[k];
}

// ---------------- kNN phase 2: merge SEG_ sorted 8-lists ----------------
__global__ __launch_bounds__(128) void knn_merge(const unsigned long long* __restrict__ part,
                                                 int* __restrict__ src) {
    int q = blockIdx.x * 128 + threadIdx.x;
    int b = q / N_;
    unsigned long long best[K_];
#pragma unroll
    for (int k = 0; k < K_; ++k) best[k] = ~0ull;
    for (int s = 0; s < SEG_; ++s) {
        const unsigned long long* lp = part + ((size_t)s * BN_ + q) * K_;
#pragma unroll
        for (int k = 0; k < K_; ++k) {
            unsigned long long key = lp[k];
            if (key >= best[K_-1]) break;
            unsigned long long cur = key;
#pragma unroll
            for (int p = 0; p < K_; ++p) {
                unsigned long long lo = best[p] < cur ? best[p] : cur;
                unsigned long long hi = best[p] < cur ? cur : best[p];
                best[p] = lo; cur = hi;
            }
        }
    }
#pragma unroll
    for (int k = 0; k < K_; ++k)
        src[(size_t)q*K_ + k] = b*N_ + (int)(best[k] & 0xFFFFFFFFu);
}

// ---------------- fused: layer-1 input cast + P4 pack + layer-1 weight prep + cvec1 ----------------
__global__ __launch_bounds__(256) void cast_prep1(const float* __restrict__ X,
                                                  unsigned short* __restrict__ Xh,
                                                  unsigned short* __restrict__ Xl,
                                                  float4* __restrict__ P4,
                                                  const float* __restrict__ W1,
                                                  const float* __restrict__ b1,
                                                  unsigned short* __restrict__ WTh,
                                                  unsigned short* __restrict__ WTl,
                                                  float* __restrict__ cvec) {
    const int total8 = BN_ * 32 / 8;     // 65536
    int t = blockIdx.x * 256 + threadIdx.x;
    if (t < total8) {
        int m = t >> 2;
        int k0 = (t & 3) * 8;
        ushort8_ vh, vl;
#pragma unroll
        for (int j = 0; j < 8; ++j) {
            int k = k0 + j;
            float v = (k < IN_) ? X[(size_t)m*IN_ + k] : 0.0f;
            unsigned short h = f2bf(v);
            vh[j] = h;
            vl[j] = f2bf(v - bf2f(h));
        }
        *(ushort8_*)(Xh + (size_t)m*32 + k0) = vh;
        *(ushort8_*)(Xl + (size_t)m*32 + k0) = vl;
        if (t < BN_) {
            const float* p = X + (size_t)t*IN_;
            float x = p[0], y = p[1], z = p[2];
            P4[t] = make_float4(x, y, z, x*x + y*y + z*z);
        }
    } else {
        int idx = t - total8;
        const int nWT = 2*64*32;         // 4096
        if (idx < nWT) {
            int n = idx >> 5;
            int k = idx & 31;
            float val = 0.0f;
            if (k < IN_) {
                if (n < 64) val = W1[(size_t)k*64 + n] - W1[(size_t)(IN_+k)*64 + n];
                else        val = W1[(size_t)(IN_+k)*64 + (n - 64)];
            }
            unsigned short h = f2bf(val);
            WTh[(size_t)n*32 + k] = h;
            WTl[(size_t)n*32 + k] = f2bf(val - bf2f(h));
        } else if (idx < nWT + 64) {
            int c = idx - nWT;
            cvec[c] = b1[c];
        }
    }
}

// ---------------- fused weight prep (layers 2,3): WT split-bf16 (BN fold) + c' vector ----------------
__global__ __launch_bounds__(256) void prep_layer(const float* __restrict__ W,
                                                  const float* __restrict__ scale,
                                                  const float* __restrict__ shift,
                                                  const float* __restrict__ bias,
                                                  unsigned short* __restrict__ WTh,
                                                  unsigned short* __restrict__ WTl,
                                                  float* __restrict__ cvec,
                                                  int Cin, int C, int Kpad) {
    int idx = blockIdx.x * 256 + threadIdx.x;
    int nWT = 2*C*Kpad;
    if (idx < nWT) {
        int n = idx / Kpad;
        int k = idx % Kpad;
        float val = 0.0f;
        if (k < Cin) {
            float s = scale[k];
            if (n < C) val = s * (W[(size_t)k*C + n] - W[(size_t)(Cin+k)*C + n]);
            else       val = s * W[(size_t)(Cin+k)*C + (n - C)];
        }
        unsigned short h = f2bf(val);
        WTh[(size_t)n*Kpad + k] = h;
        WTl[(size_t)n*Kpad + k] = f2bf(val - bf2f(h));
    } else if (idx < nWT + C) {
        int c = idx - nWT;
        float acc = bias[c];
        for (int d = 0; d < Cin; ++d) acc += shift[d] * W[(size_t)d*C + c];
        cvec[c] = acc;
    }
}

// ---------------- split-bf16 MFMA GEMM: PQ[M][Ntot] = X[M][K] @ WT^T, 128x128 tile, BK=32 ----------------
__global__ __launch_bounds__(256) void mfma_dual(const unsigned short* __restrict__ Xh,
                                                 const unsigned short* __restrict__ Xl,
                                                 const unsigned short* __restrict__ WTh,
                                                 const unsigned short* __restrict__ WTl,
                                                 float* __restrict__ PQ, int K, int Ntot,
                                                 int gx) {
    __shared__ unsigned short sXh[128*32], sXl[128*32], sWh[128*32], sWl[128*32];
    int n = blockIdx.x;
    int by = (n & 7) + 8*(n/(8*gx));    // y%8 == n%8 == XCD
    int bx = (n >> 3) % gx;
    int tid = threadIdx.x, l = tid & 63, w = tid >> 6;
    int wr = w >> 1, wc = w & 1;
    int bm = by * 128, bn0 = bx * 128;

    f32x4_ acc[4][4];
#pragma unroll
    for (int i = 0; i < 4; ++i)
#pragma unroll
        for (int j = 0; j < 4; ++j) acc[i][j] = (f32x4_){0.f, 0.f, 0.f, 0.f};

    for (int k0 = 0; k0 < K; k0 += 32) {
#pragma unroll
        for (int i = 0; i < 2; ++i) {
            int idx = tid + i*256;
            int row = idx >> 2;
            int col0 = (idx & 3) * 8;
            size_t gxo = (size_t)(bm  + row)*K + k0 + col0;
            size_t gwo = (size_t)(bn0 + row)*K + k0 + col0;
            int lo_ = ((row << 6) | (col0 << 1)) ^ ((row & 7) << 4);
            *(ushort8_*)((char*)sXh + lo_) = *(const ushort8_*)(Xh + gxo);
            *(ushort8_*)((char*)sXl + lo_) = *(const ushort8_*)(Xl + gxo);
            *(ushort8_*)((char*)sWh + lo_) = *(const ushort8_*)(WTh + gwo);
            *(ushort8_*)((char*)sWl + lo_) = *(const ushort8_*)(WTl + gwo);
        }
        __syncthreads();

        int kb = (l >> 4) << 4;
        bf16x8_ bh[4], bl4[4];
#pragma unroll
        for (int nf = 0; nf < 4; ++nf) {
            int rn = wc*64 + nf*16 + (l & 15);
            int o = ((rn << 6) | kb) ^ ((rn & 7) << 4);
            bh[nf]  = *(const bf16x8_*)((const char*)sWh + o);
            bl4[nf] = *(const bf16x8_*)((const char*)sWl + o);
        }
#pragma unroll
        for (int mf = 0; mf < 4; ++mf) {
            int rm = wr*64 + mf*16 + (l & 15);
            int o = ((rm << 6) | kb) ^ ((rm & 7) << 4);
            bf16x8_ ah = *(const bf16x8_*)((const char*)sXh + o);
            bf16x8_ al = *(const bf16x8_*)((const char*)sXl + o);
#pragma unroll
            for (int nf = 0; nf < 4; ++nf) {
                acc[mf][nf] = __builtin_amdgcn_mfma_f32_16x16x32_bf16(ah, bh[nf],  acc[mf][nf], 0, 0, 0);
                acc[mf][nf] = __builtin_amdgcn_mfma_f32_16x16x32_bf16(ah, bl4[nf], acc[mf][nf], 0, 0, 0);
                acc[mf][nf] = __builtin_amdgcn_mfma_f32_16x16x32_bf16(al, bh[nf],  acc[mf][nf], 0, 0, 0);
            }
        }
        __syncthreads();
    }

    int r0 = (l >> 4) << 2, cB = l & 15;
#pragma unroll
    for (int mf = 0; mf < 4; ++mf)
#pragma unroll
        for (int nf = 0; nf < 4; ++nf) {
            int col = bn0 + wc*64 + nf*16 + cB;
#pragma unroll
            for (int reg = 0; reg < 4; ++reg) {
                int row = bm + wr*64 + mf*16 + r0 + reg;
                PQ[(size_t)row*Ntot + col] = acc[mf][nf][reg];
            }
        }
}

// ---------------- edge combine (float4, G13): thread owns 4 channels; 16B loads/stores;
//                  src staged in LDS; LDS fold for BN partials + block max ----------------
template<int C, int GRPL>
__global__ __launch_bounds__(256) void combine_f4(
        const float* __restrict__ P, const float* __restrict__ Q,
        const float* __restrict__ cvec, const int* __restrict__ src,
        unsigned short* __restrict__ Xh_out, unsigned short* __restrict__ Xl_out,
        float* __restrict__ partial, float* __restrict__ gpart,
        int S, int chunks) {
    constexpr int VPC = C / 4;          // threads per point
    constexpr int PPR = 256 / VPC;      // points in flight per round
    constexpr int ROUNDS = GRPL / PPR;
    constexpr int NS = GRPL * K_;       // staged src ints

    int pb = blockIdx.x;
    int lb = (pb & 7) * chunks + (pb >> 3);   // XCD swizzle: batch (pb&7) -> XCD (pb&7)
    int tid = threadIdx.x;
    int tc = tid & (VPC - 1);
    int tq = tid / VPC;
    int ch0 = tc * 4;
    int i0 = lb * GRPL;

    __shared__ int ssrc[NS];
    if (tid < NS) ssrc[tid] = src[(size_t)i0 * K_ + tid];
    __syncthreads();

    f32x4_ cv = *(const f32x4_*)(cvec + ch0);
    f32x4_ sum = (f32x4_){0.f,0.f,0.f,0.f};
    f32x4_ ssq = (f32x4_){0.f,0.f,0.f,0.f};
    f32x4_ bmx = (f32x4_){-INFINITY,-INFINITY,-INFINITY,-INFINITY};

#pragma unroll
    for (int r = 0; r < ROUNDS; ++r) {
        int il = r * PPR + tq;
        int i = i0 + il;
        f32x4_ p = *(const f32x4_*)(P + (size_t)i*S + ch0) + cv;
        f32x4_ mx = (f32x4_){-INFINITY,-INFINITY,-INFINITY,-INFINITY};
#pragma unroll
        for (int k = 0; k < K_; ++k) {
            int s = ssrc[il*K_ + k];
            f32x4_ q = *(const f32x4_*)(Q + (size_t)s*S + ch0);
#pragma unroll
            for (int j = 0; j < 4; ++j) {
                float h = p[j] + q[j];
                float l = (h >= 0.f) ? h : 0.2f*h;
                sum[j] += l; ssq[j] += l*l;
                mx[j] = fmaxf(mx[j], l);
            }
        }
        if (Xh_out) {
            ushort4_ hv, lv;
#pragma unroll
            for (int j = 0; j < 4; ++j) {
                unsigned short hh = f2bf(mx[j]);
                hv[j] = hh;
                lv[j] = f2bf(mx[j] - bf2f(hh));
            }
            *(ushort4_*)(Xh_out + (size_t)i*C + ch0) = hv;
            *(ushort4_*)(Xl_out + (size_t)i*C + ch0) = lv;
        }
#pragma unroll
        for (int j = 0; j < 4; ++j) bmx[j] = fmaxf(bmx[j], mx[j]);
    }

    __shared__ f32x4_ f0[256], f1[256], f2[256];
    f0[tid] = sum; f1[tid] = ssq; f2[tid] = bmx;
    __syncthreads();
    for (int off = 128; off >= VPC; off >>= 1) {
        if (tid < off) {
            f0[tid] += f0[tid + off];
            f1[tid] += f1[tid + off];
#pragma unroll
            for (int j = 0; j < 4; ++j) f2[tid][j] = fmaxf(f2[tid][j], f2[tid + off][j]);
        }
        __syncthreads();
    }
    if (tid < VPC) {
        *(f32x4_*)(gpart + (size_t)lb*C + ch0) = f2[tid];
        *(f32x4_*)(partial + (size_t)lb*2*C + ch0)     = f0[tid];
        *(f32x4_*)(partial + (size_t)lb*2*C + C + ch0) = f1[tid];
    }
}

// ---------------- BN stats reduce -> scale/shift (deterministic tree) ----------------
__global__ __launch_bounds__(256) void reduce_kernel(const float* __restrict__ partial, int nblocks, int C,
                              const float* __restrict__ g, const float* __restrict__ be,
                              float* __restrict__ scale, float* __restrict__ shift) {
    int c = blockIdx.x;
    float s0 = 0.f, s1 = 0.f;
    for (int blk = threadIdx.x; blk < nblocks; blk += 256) {
        s0 += partial[(size_t)blk*2*C + c];
        s1 += partial[(size_t)blk*2*C + C + c];
    }
    __shared__ float l0[256], l1[256];
    l0[threadIdx.x] = s0; l1[threadIdx.x] = s1;
    __syncthreads();
    for (int off = 128; off > 0; off >>= 1) {
        if (threadIdx.x < off) {
            l0[threadIdx.x] += l0[threadIdx.x + off];
            l1[threadIdx.x] += l1[threadIdx.x + off];
        }
        __syncthreads();
    }
    if (threadIdx.x == 0) {
        float mean = l0[0] / (float)NEDGE_;
        float var  = l1[0] / (float)NEDGE_ - mean*mean;
        float sc = g[c] * rsqrtf(var + 1e-5f);
        scale[c] = sc;
        shift[c] = be[c] - mean*sc;
    }
}

// ---------------- fused global max-pool finalize (per-layer chunk counts) ----------------
__global__ __launch_bounds__(1024) void gmax_finalize(
        const float* __restrict__ gp1, const float* __restrict__ gp2, const float* __restrict__ gp3,
        const float* __restrict__ sc1, const float* __restrict__ sh1,
        const float* __restrict__ sc2, const float* __restrict__ sh2,
        const float* __restrict__ sc3, const float* __restrict__ sh3,
        float* __restrict__ gfeat) {
    int b = blockIdx.x, grp = blockIdx.y;
    const float *gp, *sc, *sh; int C, c0, coff, CH;
    if (grp == 0)      { gp = gp1; sc = sc1; sh = sh1; C = 64;  c0 = 0;          coff = 0;   CH = 128; }
    else if (grp <= 2) { gp = gp2; sc = sc2; sh = sh2; C = 128; c0 = (grp-1)*64; coff = 64;  CH = 256; }
    else               { gp = gp3; sc = sc3; sh = sh3; C = 256; c0 = (grp-3)*64; coff = 192; CH = 256; }
    int cl = threadIdx.x & 63;
    int stripe = threadIdx.x >> 6;   // 0..15
    int c = c0 + cl;
    float mx = -INFINITY;
    for (int ch = stripe; ch < CH; ch += 16)
        mx = fmaxf(mx, gp[((size_t)b*CH + ch)*C + c]);
    __shared__ float red[16][64];
    red[stripe][cl] = mx;
    __syncthreads();
    for (int off = 8; off > 0; off >>= 1) {
        if (stripe < off) red[stripe][cl] = fmaxf(red[stripe][cl], red[stripe+off][cl]);
        __syncthreads();
    }
    if (stripe == 0)
        gfeat[b*448 + coff + c] = sc[c]*red[0][cl] + sh[c];
}

// ---------------- head part 1 ----------------
__global__ __launch_bounds__(256) void final1(const float* __restrict__ gfeat,
                                              const float* __restrict__ Wf1, const float* __restrict__ bf1,
                                              const float* __restrict__ gf, const float* __restrict__ bef,
                                              float* __restrict__ H) {
    __shared__ float gfs[B_][448];
    __shared__ float red[4][64][B_];
    int t = threadIdx.x;
    int cl = t & 63;
    int stripe = t >> 6;
    int c = blockIdx.x * 64 + cl;
    for (int e = t; e < B_*448; e += 256) gfs[e/448][e%448] = gfeat[e];
    __syncthreads();
    float acc[B_] = {};
    for (int d = stripe*112; d < stripe*112 + 112; ++d) {
        float w = Wf1[(size_t)d*512 + c];
#pragma unroll
        for (int r = 0; r < B_; ++r) acc[r] += gfs[r][d] * w;
    }
#pragma unroll
    for (int r = 0; r < B_; ++r) red[stripe][cl][r] = acc[r];
    __syncthreads();
    if (stripe == 0) {
        float v[B_];
        float b1v = bf1[c];
#pragma unroll
        for (int r = 0; r < B_; ++r) {
            float a = red[0][cl][r] + red[1][cl][r] + red[2][cl][r] + red[3][cl][r] + b1v;
            v[r] = (a >= 0.f) ? a : 0.2f*a;
        }
        float mean = 0.f;
#pragma unroll
        for (int r = 0; r < B_; ++r) mean += v[r];
        mean *= (1.0f/B_);
        float var = 0.f;
#pragma unroll
        for (int r = 0; r < B_; ++r) { float dd = v[r] - mean; var += dd*dd; }
        var *= (1.0f/B_);
        float sc = gf[c] * rsqrtf(var + 1e-5f);
        float sh = bef[c] - mean*sc;
#pragma unroll
        for (int r = 0; r < B_; ++r) H[(size_t)r*512 + c] = v[r]*sc + sh;
    }
}

// ---------------- head part 2 ----------------
__global__ __launch_bounds__(128) void final2(const float* __restrict__ H,
                                              const float* __restrict__ Wf2, const float* __restrict__ bf2,
                                              float* __restrict__ out) {
    int b = blockIdx.x, c = threadIdx.x;
    __shared__ float hs[512];
    for (int e = c; e < 512; e += 128) hs[e] = H[(size_t)b*512 + e];
    __syncthreads();
    float a = bf2[c];
    for (int d = 0; d < 512; ++d) a += hs[d] * Wf2[(size_t)d*128 + c];
    out[b*128 + c] = a;
}

// ---------------- host side ----------------
extern "C" void kernel_launch(void* const* d_in, const int* in_sizes, int n_in,
                              void* d_out, int out_size, void* d_ws, size_t ws_size,
                              hipStream_t stream) {
    (void)in_sizes; (void)n_in; (void)out_size; (void)ws_size;
    const float* points = (const float*)d_in[0];
    const float* W1 = (const float*)d_in[1];  const float* b1 = (const float*)d_in[2];
    const float* g1 = (const float*)d_in[3];  const float* be1 = (const float*)d_in[4];
    const float* W2 = (const float*)d_in[5];  const float* b2 = (const float*)d_in[6];
    const float* g2 = (const float*)d_in[7];  const float* be2 = (const float*)d_in[8];
    const float* W3 = (const float*)d_in[9];  const float* b3 = (const float*)d_in[10];
    const float* g3 = (const float*)d_in[11]; const float* be3 = (const float*)d_in[12];
    const float* Wf1 = (const float*)d_in[13]; const float* bf1 = (const float*)d_in[14];
    const float* gf = (const float*)d_in[15];  const float* bef = (const float*)d_in[16];
    const float* Wf2 = (const float*)d_in[17]; const float* bf2 = (const float*)d_in[18];
    float* out = (float*)d_out;

    size_t off = 0;
    char* base = (char*)d_ws;
    auto carve = [&](size_t bytes) -> void* {
        void* p = base + off;
        off += (bytes + 255) & ~(size_t)255;
        return p;
    };
    int*   src     = (int*)  carve((size_t)NEDGE_ * 4);
    float* PQ      = (float*)carve((size_t)BN_ * 512 * 4);   // 32MB; also kNN partial overlay
    float* gp1     = (float*)carve((size_t)(BN_/16) * 64 * 4);
    float* gp2     = (float*)carve((size_t)(BN_/8) * 128 * 4);
    float* gp3     = (float*)carve((size_t)(BN_/8) * 256 * 4);
    unsigned short* XhA = (unsigned short*)carve((size_t)BN_ * 128 * 2);
    unsigned short* XlA = (unsigned short*)carve((size_t)BN_ * 128 * 2);
    unsigned short* XhB = (unsigned short*)carve((size_t)BN_ * 128 * 2);
    unsigned short* XlB = (unsigned short*)carve((size_t)BN_ * 128 * 2);
    unsigned short* WTh = (unsigned short*)carve((size_t)512 * 128 * 2);
    unsigned short* WTl = (unsigned short*)carve((size_t)512 * 128 * 2);
    float4* P4     = (float4*)carve((size_t)BN_ * 16);
    float* cvec    = (float*)carve(256 * 4);
    float* sc1     = (float*)carve(64 * 4);
    float* sh1     = (float*)carve(64 * 4);
    float* sc2     = (float*)carve(128 * 4);
    float* sh2     = (float*)carve(128 * 4);
    float* sc3     = (float*)carve(256 * 4);
    float* sh3     = (float*)carve(256 * 4);
    float* partial = (float*)carve((size_t)(BN_/8) * 2 * 256 * 4);
    float* gfeat   = (float*)carve((size_t)B_ * 448 * 4);
    float* H       = (float*)carve((size_t)B_ * 512 * 4);

    // fused: cast layer-1 input + P4 pack + layer-1 weight prep + cvec1
    cast_prep1<<<(65536 + 4096 + 64 + 255)/256, 256, 0, stream>>>(
        points, XhA, XlA, P4, W1, b1, WTh, WTl, cvec);

    // kNN: phase-1 partials (32MB) overlay PQ (dead until first mfma_dual)
    unsigned long long* part = (unsigned long long*)PQ;
    knn_part<<<dim3(BN_/256, SEG_), 256, 0, stream>>>(P4, part);
    knn_merge<<<BN_/128, 128, 0, stream>>>(part, src);

    // ---- layer 1 (prep done in cast_prep1) ----
    mfma_dual<<<1*(BN_/128), 256, 0, stream>>>(XhA, XlA, WTh, WTl, PQ, 32, 128, 1);
    combine_f4<64,16><<<BN_/16, 256, 0, stream>>>(PQ, PQ + 64, cvec, src, XhB, XlB,
                                                  partial, gp1, 128, 128);
    reduce_kernel<<<64, 256, 0, stream>>>(partial, BN_/16, 64, g1, be1, sc1, sh1);

    // ---- layer 2 ----
    prep_layer<<<(2*128*64 + 128 + 255)/256, 256, 0, stream>>>(W2, sc1, sh1, b2, WTh, WTl, cvec, 64, 128, 64);
    mfma_dual<<<2*(BN_/128), 256, 0, stream>>>(XhB, XlB, WTh, WTl, PQ, 64, 256, 2);
    combine_f4<128,8><<<BN_/8, 256, 0, stream>>>(PQ, PQ + 128, cvec, src, XhA, XlA,
                                                 partial, gp2, 256, 256);
    reduce_kernel<<<128, 256, 0, stream>>>(partial, BN_/8, 128, g2, be2, sc2, sh2);

    // ---- layer 3 ----
    prep_layer<<<(2*256*128 + 256 + 255)/256, 256, 0, stream>>>(W3, sc2, sh2, b3, WTh, WTl, cvec, 128, 256, 128);
    mfma_dual<<<4*(BN_/128), 256, 0, stream>>>(XhA, XlA, WTh, WTl, PQ, 128, 512, 4);
    combine_f4<256,8><<<BN_/8, 256, 0, stream>>>(PQ, PQ + 256, cvec, src, nullptr, nullptr,
                                                 partial, gp3, 512, 256);
    reduce_kernel<<<256, 256, 0, stream>>>(partial, BN_/8, 256, g3, be3, sc3, sh3);

    gmax_finalize<<<dim3(B_, 7), 1024, 0, stream>>>(gp1, gp2, gp3,
                                                    sc1, sh1, sc2, sh2, sc3, sh3, gfeat);

    final1<<<8, 256, 0, stream>>>(gfeat, Wf1, bf1, gf, bef, H);
    final2<<<8, 128, 0, stream>>>(H, Wf2, bf2, out);
}